// Round 6
// baseline (171.020 us; speedup 1.0000x reference)
//
#include <hip/hip_runtime.h>

#define B_    2
#define T_    2048
#define C_    1024
#define H_    16
#define DH_   64
#define M_    (B_ * T_)        // 4096 tokens
#define NQKV  (3 * C_)         // 3072

typedef __bf16 bf16;
typedef __bf16 bf16x2 __attribute__((ext_vector_type(2)));
typedef __bf16 bf16x4 __attribute__((ext_vector_type(4)));
typedef __bf16 bf16x8 __attribute__((ext_vector_type(8)));
typedef float  f32x4  __attribute__((ext_vector_type(4)));
typedef float  f32x16 __attribute__((ext_vector_type(16)));
typedef unsigned u32x4 __attribute__((ext_vector_type(4)));

// async global->LDS, 16B per lane (global_load_lds_dwordx4).
// LDS dest must be wave-uniform base + lane*16 (no per-lane scatter).
__device__ __forceinline__ void async16(const void* g, void* l) {
  __builtin_amdgcn_global_load_lds(
      (const __attribute__((address_space(1))) void*)g,
      (__attribute__((address_space(3))) void*)l, 16, 0, 0);
}

// pack two f32 -> one dword of 2 bf16 (lo in bits 0-15)
__device__ __forceinline__ unsigned pk(float a, float b) {
  bf16x2 t; t[0] = (bf16)a; t[1] = (bf16)b;
  return __builtin_bit_cast(unsigned, t);
}

// ---------------------------------------------------------------- fused prep
__global__ __launch_bounds__(256) void prep_k(
    const float* __restrict__ x, bf16* __restrict__ xbf,
    const float* __restrict__ Wqkv, bf16* __restrict__ wqkvT,
    const float* __restrict__ Wproj, bf16* __restrict__ wprojT) {
  __shared__ float tile[32][33];
  const int bid = blockIdx.x;
  if (bid < 4096) {                              // ---- cvt x
    const int i = (bid * 256 + threadIdx.x) * 4;
    float4 v = *(const float4*)(x + i);
    bf16x4 o;
    o[0] = (bf16)v.x; o[1] = (bf16)v.y; o[2] = (bf16)v.z; o[3] = (bf16)v.w;
    *(bf16x4*)(xbf + i) = o;
    return;
  }
  const float* in; bf16* out; int R, C, cb, rb;
  if (bid < 4096 + 3072) {                       // ---- Wqkv [1024 x 3072]
    const int b = bid - 4096;
    in = Wqkv; out = wqkvT; R = 1024; C = 3072; cb = b % 96; rb = b / 96;
  } else {                                       // ---- Wproj [1024 x 1024]
    const int b = bid - 7168;
    in = Wproj; out = wprojT; R = 1024; C = 1024; cb = b & 31; rb = b >> 5;
  }
  const int c0 = cb * 32, r0 = rb * 32;
  const int tx = threadIdx.x & 31, ty = threadIdx.x >> 5;
#pragma unroll
  for (int j = 0; j < 4; j++)
    tile[ty + j * 8][tx] = in[(size_t)(r0 + ty + j * 8) * C + c0 + tx];
  __syncthreads();
#pragma unroll
  for (int j = 0; j < 4; j++)
    out[(size_t)(c0 + ty + j * 8) * R + r0 + tx] = (bf16)tile[tx][ty + j * 8];
}

// ---------------------------------------------------------------- GEMM
// C[M,N] = A[M,K=1024] * Bt[N,K]^T (+bias). Tile BM x 128, BK=64, 4 waves
// (2x2 of (BM/2)x64). r5 retune: QKV now BM=128 (the m97-verified 128^2
// geometry, 874-912 TF refcheck'd at this shape; 32KB LDS, grid 768 = 3/CU,
// ~164 VGPR = 3 waves/SIMD exact fit). The old BM=64 tile had HALF the
// arithmetic intensity (43.7 vs 87 FLOP/B staged) and needed 6 blocks/CU to
// reach only ~630 TF. Proj stays TLP-bound -> BM=32 (grid 1024 = 4/CU,
// 20KB LDS). Rows 128B, groups XOR-swizzled by row&7 (2-way = free).
template <int EPI, int BM>
__global__ __launch_bounds__(256) void gemm_k(
    const bf16* __restrict__ A, const bf16* __restrict__ Bt,
    const float* __restrict__ bias, float* __restrict__ outF,
    bf16* __restrict__ qb, bf16* __restrict__ kb, bf16* __restrict__ vtb) {
  constexpr int K = 1024;
  constexpr int MI = BM / 32;                    // m-frags per wave
  __shared__ alignas(16) bf16 As[BM * 64];
  __shared__ alignas(16) bf16 Bs[128 * 64];
  const int tid = threadIdx.x;
  const int lane = tid & 63, wv = tid >> 6;
  const int l15 = lane & 15, quad = lane >> 4;
  const int wm = (wv >> 1) * (BM / 2), wn = (wv & 1) * 64;
  const int m0 = blockIdx.x * BM, n0 = blockIdx.y * 128;

  f32x4 acc[MI][4] = {};

  const int srow = tid >> 3;                     // 0..31 (+32/call)
  const int sgb = ((tid & 7) ^ (srow & 7)) * 8;
  const bf16* ga = A + (size_t)(m0 + srow) * K + sgb;
  const bf16* gb = Bt + (size_t)(n0 + srow) * K + sgb;
  const int swz = l15 & 7;                       // read-side swizzle key

  for (int it = 0; it < K / 64; ++it) {
    const int k0 = it * 64;
#pragma unroll
    for (int c = 0; c < BM / 32; c++)            // A: BM rows, 32/call
      async16(ga + k0 + (size_t)(c * 32) * K, As + tid * 8 + c * 2048);
#pragma unroll
    for (int c = 0; c < 4; c++)                  // B: 128 rows
      async16(gb + k0 + (size_t)(c * 32) * K, Bs + tid * 8 + c * 2048);
    __syncthreads();
    bf16x8 af[2][MI], bfr[2][4];
#pragma unroll
    for (int kk = 0; kk < 2; kk++) {
#pragma unroll
      for (int i = 0; i < MI; i++)
        af[kk][i] = *(const bf16x8*)(As + (wm + i * 16 + l15) * 64 +
                                     (((kk * 4 + quad) ^ swz) << 3));
#pragma unroll
      for (int j = 0; j < 4; j++)
        bfr[kk][j] = *(const bf16x8*)(Bs + (wn + j * 16 + l15) * 64 +
                                      (((kk * 4 + quad) ^ swz) << 3));
    }
#pragma unroll
    for (int kk = 0; kk < 2; kk++)
#pragma unroll
      for (int i = 0; i < MI; i++)
#pragma unroll
        for (int j = 0; j < 4; j++)
          acc[i][j] = __builtin_amdgcn_mfma_f32_16x16x32_bf16(
              af[kk][i], bfr[kk][j], acc[i][j], 0, 0, 0);
    __syncthreads();
  }

  // epilogue: C/D layout col=lane&15, row=quad*4+reg
#pragma unroll
  for (int i = 0; i < MI; i++) {
#pragma unroll
    for (int j = 0; j < 4; j++) {
      const int gcol = n0 + wn + j * 16 + l15;
      const float bv = bias[gcol];
      const int trow = m0 + wm + i * 16 + quad * 4;   // grow base (4-aligned)
      if constexpr (EPI == 0) {
        const int which = gcol >> 10;            // 0=Q 1=K 2=V
        const int hn = gcol & 1023;
        const int h = hn >> 6, d = hn & 63;
        const int bb = trow >> 11, t = trow & 2047;
        const int head = bb * 16 + h;            // 0..31
        if (which == 0) {
#pragma unroll
          for (int r = 0; r < 4; r++)
            qb[head * 131072 + (t + r) * 64 + d] =
                (bf16)((acc[i][j][r] + bv) * 0.1803368801f); // 1/8 * log2(e)
        } else if (which == 1) {
#pragma unroll
          for (int r = 0; r < 4; r++)
            kb[head * 131072 + (t + r) * 64 + d] = (bf16)(acc[i][j][r] + bv);
        } else {
          bf16x4 pv;                             // t-contiguous in V^T [d][t]
#pragma unroll
          for (int r = 0; r < 4; r++) pv[r] = (bf16)(acc[i][j][r] + bv);
          *(bf16x4*)(vtb + head * 131072 + d * 2048 + t) = pv;
        }
      } else {
#pragma unroll
        for (int r = 0; r < 4; r++)
          outF[(size_t)(trow + r) * 1024 + gcol] = acc[i][j][r] + bv;
      }
    }
  }
}

// ---------------------------------------------------------------- flash attention
// (r4 split-kt structure, unchanged) 512 blocks x 512 threads (8 waves).
// Waves 0-3 = q sub-blocks of 32 x kt-half 0; waves 4-7 = same q rows x
// kt-half 1. Per-wave (m, lsum, o); one LDS merge at the end. 16 waves/CU
// (4/SIMD) at 64KB LDS (2 blocks/CU). Same (x,15-x) CU pairing + b&7 XCD pin.
__global__ __launch_bounds__(512, 4) void attn_k(const bf16* __restrict__ Q,
                                                 const bf16* __restrict__ K,
                                                 const bf16* __restrict__ Vt,
                                                 bf16* __restrict__ O) {
  __shared__ alignas(16) bf16 Ks[2][128 * 64];   // [kt][d], 8-group swizzle, dbuf
  __shared__ alignas(16) bf16 Vs[2][64 * 128];   // [d][kt], 16-group swizzle, dbuf
  const int tid = threadIdx.x, lane = tid & 63, wv = tid >> 6;  // wv 0..7
  const int l31 = lane & 31, hi = lane >> 5;
  const int qs = wv & 3, halfw = wv >> 2;        // q sub-block / kt half

  const int b = blockIdx.x;                      // 0..511
  const int sH = b >> 8, i = b & 255;
  const int bh = (i & 7) | (((i >> 3) & 3) << 3);  // head 0..31, b&7 = XCD
  const int x = i >> 5;                          // 0..7
  const int qJ = sH ? (15 - x) : x;
  const int q0 = qJ * 128;
  const int nIter = qJ + 1;

  const bf16* Qb = Q + (size_t)bh * 131072;
  const bf16* Kb = K + (size_t)bh * 131072;
  const bf16* Vb = Vt + (size_t)bh * 131072;

  const int krow = tid >> 3;                     // 0..63 (+64 on 2nd call)
  const int kg = (tid & 7) ^ (krow & 7);
  const bf16* gk = Kb + krow * 64 + kg * 8;
  const int vrow = tid >> 4;                     // 0..31 (+32 on 2nd call)
  const int vg = (tid & 15) ^ (vrow & 15);
  const bf16* gv = Vb + vrow * 2048 + vg * 8;

  const int swzk = l31 & 7;                      // K read swizzle key
  const int swzv = l31 & 15;                     // V read swizzle key
  const int bb = bh >> 4, h = bh & 15;

  const int q = q0 + qs * 32 + l31;              // this lane's q row
  bf16x8 aq[4];                                  // Q[q][ds*16 + hi*8 ..+8]
#pragma unroll
  for (int ds = 0; ds < 4; ds++)
    aq[ds] = *(const bf16x8*)(Qb + q * 64 + ds * 16 + hi * 8);

  f32x16 o0 = {}, o1 = {};                       // O^T: d = (r&3)+8*(r>>2)+4*hi (+32 o1)
  float m = -3.0e38f, lsum = 0.f;

  // prologue: stage kt-tile 0 into buf 0 (4 x async16 per thread, 32KB)
#pragma unroll
  for (int c = 0; c < 2; c++) {
    async16(gk + c * (64 * 64), &Ks[0][tid * 8 + c * 4096]);
    async16(gv + c * (32 * 2048), &Vs[0][tid * 8 + c * 4096]);
  }

  for (int it = 0; it < nIter; ++it) {
    const int cur = it & 1;
    __syncthreads();                             // buf[cur] resident (vmcnt drained)
    if (it + 1 < nIter) {                        // prefetch next tile into buf[cur^1]
      const int kt1 = (it + 1) * 128;
#pragma unroll
      for (int c = 0; c < 2; c++) {
        async16(gk + kt1 * 64 + c * (64 * 64), &Ks[cur ^ 1][tid * 8 + c * 4096]);
        async16(gv + kt1 + c * (32 * 2048), &Vs[cur ^ 1][tid * 8 + c * 4096]);
      }
    }
    const bf16* Kc = Ks[cur];
    const bf16* Vc = Vs[cur];

    // QK^T over this wave's kt-half:
    // s[nf] = S[kt = it*128 + halfw*64 + nf*32 + (r&3)+8*(r>>2)+4*hi][q]
    f32x16 s[2] = {};
    __builtin_amdgcn_s_setprio(1);
#pragma unroll
    for (int nf = 0; nf < 2; nf++) {
      const int row = halfw * 64 + nf * 32 + l31;
#pragma unroll
      for (int ds = 0; ds < 4; ds++) {
        bf16x8 kf = *(const bf16x8*)(Kc + row * 64 + (((ds * 2 + hi) ^ swzk) << 3));
        s[nf] = __builtin_amdgcn_mfma_f32_32x32x16_bf16(kf, aq[ds], s[nf], 0, 0, 0);
      }
    }
    __builtin_amdgcn_s_setprio(0);

    if (it == nIter - 1) {                       // diagonal tile mask
#pragma unroll
      for (int nf = 0; nf < 2; nf++)
#pragma unroll
        for (int r = 0; r < 16; r++) {
          const int kt = it * 128 + halfw * 64 + nf * 32 +
                         (r & 3) + 8 * (r >> 2) + 4 * hi;
          if (kt > q) s[nf][r] = -3.0e38f;
        }
    }

    // online softmax over 32 local kt (+partner lane^32 = other 16 rows/32-blk).
    // explicit fmax tree (depth 5) instead of 32-deep serial chain.
    float red[8];
#pragma unroll
    for (int r = 0; r < 8; r++)
      red[r] = fmaxf(fmaxf(s[0][r], s[0][r + 8]), fmaxf(s[1][r], s[1][r + 8]));
#pragma unroll
    for (int st = 4; st >= 1; st >>= 1)
#pragma unroll
      for (int r = 0; r < 4; r++)
        if (r < st) red[r] = fmaxf(red[r], red[r + st]);
    float mx = red[0];
    mx = fmaxf(mx, __shfl_xor(mx, 32));
    if (!__all(mx - m <= 8.0f)) {                // defer-max (T13, THR=8 log2)
      const float mnew = fmaxf(m, mx);
      const float alpha = __builtin_amdgcn_exp2f(m - mnew);
      m = mnew; lsum *= alpha;
#pragma unroll
      for (int r = 0; r < 16; r++) { o0[r] *= alpha; o1[r] *= alpha; }
    }
    float tsp[4] = {0.f, 0.f, 0.f, 0.f};
    unsigned w[2][8];                            // w[nf][k]: kt pair base
                                                 // {0,2,8,10,16,18,24,26}[k]+4*hi
#pragma unroll
    for (int nf = 0; nf < 2; nf++)
#pragma unroll
      for (int k = 0; k < 8; k++) {
        const float pa = __builtin_amdgcn_exp2f(s[nf][2 * k] - m);
        const float pc = __builtin_amdgcn_exp2f(s[nf][2 * k + 1] - m);
        tsp[k & 3] += pa + pc;
        w[nf][k] = pk(pa, pc);
      }
    float ts = (tsp[0] + tsp[1]) + (tsp[2] + tsp[3]);
    ts += __shfl_xor(ts, 32);
    lsum += ts;

    // PV over this wave's kt-half. Chunk c needs pb[j] = P[c*16+hi*8+j][q]:
    //   hi=0: [own w(4h+0..1), partner w(4h+0..1)]
    //   hi=1: [partner w(4h+2..3), own w(4h+2..3)]
    __builtin_amdgcn_s_setprio(1);
#pragma unroll
    for (int nf = 0; nf < 2; nf++) {
#pragma unroll
      for (int hh = 0; hh < 2; hh++) {
        const unsigned w0 = w[nf][hh * 4 + 0], w1 = w[nf][hh * 4 + 1];
        const unsigned w2 = w[nf][hh * 4 + 2], w3 = w[nf][hh * 4 + 3];
        const unsigned rx = (unsigned)__shfl_xor((int)(hi ? w0 : w2), 32);
        const unsigned ry = (unsigned)__shfl_xor((int)(hi ? w1 : w3), 32);
        u32x4 pw;
        pw[0] = hi ? rx : w0;
        pw[1] = hi ? ry : w1;
        pw[2] = hi ? w2 : rx;
        pw[3] = hi ? w3 : ry;
        const bf16x8 pb = __builtin_bit_cast(bf16x8, pw);
        const int c = halfw * 4 + nf * 2 + hh;   // global 16-kt chunk 0..7
        const bf16x8 vf0 = *(const bf16x8*)(Vc + l31 * 128 +
                                            (((c * 2 + hi) ^ swzv) << 3));
        o0 = __builtin_amdgcn_mfma_f32_32x32x16_bf16(vf0, pb, o0, 0, 0, 0);
        const bf16x8 vf1 = *(const bf16x8*)(Vc + (32 + l31) * 128 +
                                            (((c * 2 + hi) ^ swzv) << 3));
        o1 = __builtin_amdgcn_mfma_f32_32x32x16_bf16(vf1, pb, o1, 0, 0, 0);
      }
    }
    __builtin_amdgcn_s_setprio(0);
  }

  // ---- merge the two kt-halves (waves w and w+4 share q rows) ----
  __syncthreads();                               // all LDS use done
  float* oX = (float*)Vs;                        // 8192 f32: [32][256] r-major
  float* mX = (float*)Ks;                        // [2][256]: m then lsum
  const int slot = qs * 64 + lane;               // 0..255
  if (halfw == 1) {
#pragma unroll
    for (int r = 0; r < 16; r++) {
      oX[r * 256 + slot] = o0[r];
      oX[(16 + r) * 256 + slot] = o1[r];
    }
    mX[slot] = m;
    mX[256 + slot] = lsum;
  }
  __syncthreads();
  if (halfw == 0) {
    const float mB = mX[slot], lB = mX[256 + slot];
    const float m12 = fmaxf(m, mB);
    const float aA = __builtin_amdgcn_exp2f(m - m12);
    const float aB = __builtin_amdgcn_exp2f(mB - m12);
    const float inv = 1.0f / (lsum * aA + lB * aB);
    bf16* Op = O + (size_t)(bb * 2048 + q) * 1024 + h * 64;
#pragma unroll
    for (int g = 0; g < 4; g++) {
      bf16x4 v0, v1;
#pragma unroll
      for (int k2 = 0; k2 < 4; k2++) {
        const int r = g * 4 + k2;
        v0[k2] = (bf16)((o0[r] * aA + oX[r * 256 + slot] * aB) * inv);
        v1[k2] = (bf16)((o1[r] * aA + oX[(16 + r) * 256 + slot] * aB) * inv);
      }
      *(bf16x4*)(Op + g * 8 + hi * 4) = v0;
      *(bf16x4*)(Op + 32 + g * 8 + hi * 4) = v1;
    }
  }
}

// ---------------------------------------------------------------- launch
extern "C" void kernel_launch(void* const* d_in, const int* in_sizes, int n_in,
                              void* d_out, int out_size, void* d_ws, size_t ws_size,
                              hipStream_t stream) {
  const float* x     = (const float*)d_in[0];
  const float* Wqkv  = (const float*)d_in[1];
  const float* bqkv  = (const float*)d_in[2];
  const float* Wproj = (const float*)d_in[3];
  const float* bproj = (const float*)d_in[4];
  float* out = (float*)d_out;

  char* p = (char*)d_ws;
  bf16* xbf    = (bf16*)p; p += (size_t)M_ * C_ * 2;     // 8 MB
  bf16* wqkvT  = (bf16*)p; p += (size_t)NQKV * C_ * 2;   // 6 MB
  bf16* wprojT = (bf16*)p; p += (size_t)C_ * C_ * 2;     // 2 MB
  bf16* Qb     = (bf16*)p; p += (size_t)M_ * C_ * 2;     // 8 MB
  bf16* Kb     = (bf16*)p; p += (size_t)M_ * C_ * 2;     // 8 MB
  bf16* Vtb    = (bf16*)p; p += (size_t)M_ * C_ * 2;     // 8 MB
  bf16* AO     = (bf16*)p;                               // 8 MB (total 48 MB)

  prep_k<<<8192, 256, 0, stream>>>(x, xbf, Wqkv, wqkvT, Wproj, wprojT);

  // QKV: m97 geometry — 128x128 tile, grid 32x24 = 768 blocks = 3/CU
  gemm_k<0, 128><<<dim3(M_ / 128, NQKV / 128), 256, 0, stream>>>(
      xbf, wqkvT, bqkv, nullptr, Qb, Kb, Vtb);

  attn_k<<<512, 512, 0, stream>>>(Qb, Kb, Vtb, AO);

  // proj: TLP-bound — 32x128 tile, grid 128x8 = 1024 blocks = 4/CU
  gemm_k<1, 32><<<dim3(M_ / 32, C_ / 128), 256, 0, stream>>>(
      AO, wprojT, bproj, out, nullptr, nullptr, nullptr);
}

// Round 7
// 165.766 us; speedup vs baseline: 1.0317x; 1.0317x over previous
//
#include <hip/hip_runtime.h>

#define B_    2
#define T_    2048
#define C_    1024
#define H_    16
#define DH_   64
#define M_    (B_ * T_)        // 4096 tokens
#define NQKV  (3 * C_)         // 3072

typedef __bf16 bf16;
typedef __bf16 bf16x2 __attribute__((ext_vector_type(2)));
typedef __bf16 bf16x4 __attribute__((ext_vector_type(4)));
typedef __bf16 bf16x8 __attribute__((ext_vector_type(8)));
typedef float  f32x4  __attribute__((ext_vector_type(4)));
typedef float  f32x16 __attribute__((ext_vector_type(16)));
typedef unsigned u32x4 __attribute__((ext_vector_type(4)));

// async global->LDS, 16B per lane (global_load_lds_dwordx4).
// LDS dest must be wave-uniform base + lane*16 (no per-lane scatter).
__device__ __forceinline__ void async16(const void* g, void* l) {
  __builtin_amdgcn_global_load_lds(
      (const __attribute__((address_space(1))) void*)g,
      (__attribute__((address_space(3))) void*)l, 16, 0, 0);
}

// pack two f32 -> one dword of 2 bf16 (lo in bits 0-15)
__device__ __forceinline__ unsigned pk(float a, float b) {
  bf16x2 t; t[0] = (bf16)a; t[1] = (bf16)b;
  return __builtin_bit_cast(unsigned, t);
}

// ---------------------------------------------------------------- fused prep
__global__ __launch_bounds__(256) void prep_k(
    const float* __restrict__ x, bf16* __restrict__ xbf,
    const float* __restrict__ Wqkv, bf16* __restrict__ wqkvT,
    const float* __restrict__ Wproj, bf16* __restrict__ wprojT) {
  __shared__ float tile[32][33];
  const int bid = blockIdx.x;
  if (bid < 4096) {                              // ---- cvt x
    const int i = (bid * 256 + threadIdx.x) * 4;
    float4 v = *(const float4*)(x + i);
    bf16x4 o;
    o[0] = (bf16)v.x; o[1] = (bf16)v.y; o[2] = (bf16)v.z; o[3] = (bf16)v.w;
    *(bf16x4*)(xbf + i) = o;
    return;
  }
  const float* in; bf16* out; int R, C, cb, rb;
  if (bid < 4096 + 3072) {                       // ---- Wqkv [1024 x 3072]
    const int b = bid - 4096;
    in = Wqkv; out = wqkvT; R = 1024; C = 3072; cb = b % 96; rb = b / 96;
  } else {                                       // ---- Wproj [1024 x 1024]
    const int b = bid - 7168;
    in = Wproj; out = wprojT; R = 1024; C = 1024; cb = b & 31; rb = b >> 5;
  }
  const int c0 = cb * 32, r0 = rb * 32;
  const int tx = threadIdx.x & 31, ty = threadIdx.x >> 5;
#pragma unroll
  for (int j = 0; j < 4; j++)
    tile[ty + j * 8][tx] = in[(size_t)(r0 + ty + j * 8) * C + c0 + tx];
  __syncthreads();
#pragma unroll
  for (int j = 0; j < 4; j++)
    out[(size_t)(c0 + ty + j * 8) * R + r0 + tx] = (bf16)tile[tx][ty + j * 8];
}

// ---------------------------------------------------------------- GEMM
// C[M,N] = A[M,K=1024] * Bt[N,K]^T (+bias). Tile BM x BN, BK=64, 4 waves
// (2x2 of (BM/2)x(BN/2)). QKV: 128x128 (m97-verified geometry, 874-912 TF
// refcheck'd at this shape; 32KB LDS, grid 768 = 3/CU). Proj (r6 retune):
// 64x64 — same 1024-block grid (4/CU TLP) as r5's 32x128 but 32.7 vs 25.6
// FLOP/B staging intensity and 16KB LDS. Rows 128B, groups XOR-swizzled by
// row&7 (2-way = free).
template <int EPI, int BM, int BN>
__global__ __launch_bounds__(256) void gemm_k(
    const bf16* __restrict__ A, const bf16* __restrict__ Bt,
    const float* __restrict__ bias, float* __restrict__ outF,
    bf16* __restrict__ qb, bf16* __restrict__ kb, bf16* __restrict__ vtb) {
  constexpr int K = 1024;
  constexpr int MI = BM / 32;                    // m-frags per wave
  constexpr int NJ = BN / 32;                    // n-frags per wave
  __shared__ alignas(16) bf16 As[BM * 64];
  __shared__ alignas(16) bf16 Bs[BN * 64];
  const int tid = threadIdx.x;
  const int lane = tid & 63, wv = tid >> 6;
  const int l15 = lane & 15, quad = lane >> 4;
  const int wm = (wv >> 1) * (BM / 2), wn = (wv & 1) * (BN / 2);
  const int m0 = blockIdx.x * BM, n0 = blockIdx.y * BN;

  f32x4 acc[MI][NJ] = {};

  const int srow = tid >> 3;                     // 0..31 (+32/call)
  const int sgb = ((tid & 7) ^ (srow & 7)) * 8;
  const bf16* ga = A + (size_t)(m0 + srow) * K + sgb;
  const bf16* gb = Bt + (size_t)(n0 + srow) * K + sgb;
  const int swz = l15 & 7;                       // read-side swizzle key

  for (int it = 0; it < K / 64; ++it) {
    const int k0 = it * 64;
#pragma unroll
    for (int c = 0; c < BM / 32; c++)            // A: BM rows, 32/call
      async16(ga + k0 + (size_t)(c * 32) * K, As + tid * 8 + c * 2048);
#pragma unroll
    for (int c = 0; c < BN / 32; c++)            // B: BN rows, 32/call
      async16(gb + k0 + (size_t)(c * 32) * K, Bs + tid * 8 + c * 2048);
    __syncthreads();
    bf16x8 af[2][MI], bfr[2][NJ];
#pragma unroll
    for (int kk = 0; kk < 2; kk++) {
#pragma unroll
      for (int i = 0; i < MI; i++)
        af[kk][i] = *(const bf16x8*)(As + (wm + i * 16 + l15) * 64 +
                                     (((kk * 4 + quad) ^ swz) << 3));
#pragma unroll
      for (int j = 0; j < NJ; j++)
        bfr[kk][j] = *(const bf16x8*)(Bs + (wn + j * 16 + l15) * 64 +
                                      (((kk * 4 + quad) ^ swz) << 3));
    }
#pragma unroll
    for (int kk = 0; kk < 2; kk++)
#pragma unroll
      for (int i = 0; i < MI; i++)
#pragma unroll
        for (int j = 0; j < NJ; j++)
          acc[i][j] = __builtin_amdgcn_mfma_f32_16x16x32_bf16(
              af[kk][i], bfr[kk][j], acc[i][j], 0, 0, 0);
    __syncthreads();
  }

  // epilogue: C/D layout col=lane&15, row=quad*4+reg
#pragma unroll
  for (int i = 0; i < MI; i++) {
#pragma unroll
    for (int j = 0; j < NJ; j++) {
      const int gcol = n0 + wn + j * 16 + l15;
      const float bv = bias[gcol];
      const int trow = m0 + wm + i * 16 + quad * 4;   // grow base (4-aligned)
      if constexpr (EPI == 0) {
        const int which = gcol >> 10;            // 0=Q 1=K 2=V
        const int hn = gcol & 1023;
        const int h = hn >> 6, d = hn & 63;
        const int bb = trow >> 11, t = trow & 2047;
        const int head = bb * 16 + h;            // 0..31
        if (which == 0) {
#pragma unroll
          for (int r = 0; r < 4; r++)
            qb[head * 131072 + (t + r) * 64 + d] =
                (bf16)((acc[i][j][r] + bv) * 0.1803368801f); // 1/8 * log2(e)
        } else if (which == 1) {
#pragma unroll
          for (int r = 0; r < 4; r++)
            kb[head * 131072 + (t + r) * 64 + d] = (bf16)(acc[i][j][r] + bv);
        } else {
          bf16x4 pv;                             // t-contiguous in V^T [d][t]
#pragma unroll
          for (int r = 0; r < 4; r++) pv[r] = (bf16)(acc[i][j][r] + bv);
          *(bf16x4*)(vtb + head * 131072 + d * 2048 + t) = pv;
        }
      } else {
#pragma unroll
        for (int r = 0; r < 4; r++)
          outF[(size_t)(trow + r) * 1024 + gcol] = acc[i][j][r] + bv;
      }
    }
  }
}

// ---------------------------------------------------------------- flash attention
// (r4 split-kt structure, unchanged) 512 blocks x 512 threads (8 waves).
// Waves 0-3 = q sub-blocks of 32 x kt-half 0; waves 4-7 = same q rows x
// kt-half 1. Per-wave (m, lsum, o); one LDS merge at the end. 16 waves/CU
// (4/SIMD) at 64KB LDS (2 blocks/CU). Same (x,15-x) CU pairing + b&7 XCD pin.
__global__ __launch_bounds__(512, 4) void attn_k(const bf16* __restrict__ Q,
                                                 const bf16* __restrict__ K,
                                                 const bf16* __restrict__ Vt,
                                                 bf16* __restrict__ O) {
  __shared__ alignas(16) bf16 Ks[2][128 * 64];   // [kt][d], 8-group swizzle, dbuf
  __shared__ alignas(16) bf16 Vs[2][64 * 128];   // [d][kt], 16-group swizzle, dbuf
  const int tid = threadIdx.x, lane = tid & 63, wv = tid >> 6;  // wv 0..7
  const int l31 = lane & 31, hi = lane >> 5;
  const int qs = wv & 3, halfw = wv >> 2;        // q sub-block / kt half

  const int b = blockIdx.x;                      // 0..511
  const int sH = b >> 8, i = b & 255;
  const int bh = (i & 7) | (((i >> 3) & 3) << 3);  // head 0..31, b&7 = XCD
  const int x = i >> 5;                          // 0..7
  const int qJ = sH ? (15 - x) : x;
  const int q0 = qJ * 128;
  const int nIter = qJ + 1;

  const bf16* Qb = Q + (size_t)bh * 131072;
  const bf16* Kb = K + (size_t)bh * 131072;
  const bf16* Vb = Vt + (size_t)bh * 131072;

  const int krow = tid >> 3;                     // 0..63 (+64 on 2nd call)
  const int kg = (tid & 7) ^ (krow & 7);
  const bf16* gk = Kb + krow * 64 + kg * 8;
  const int vrow = tid >> 4;                     // 0..31 (+32 on 2nd call)
  const int vg = (tid & 15) ^ (vrow & 15);
  const bf16* gv = Vb + vrow * 2048 + vg * 8;

  const int swzk = l31 & 7;                      // K read swizzle key
  const int swzv = l31 & 15;                     // V read swizzle key
  const int bb = bh >> 4, h = bh & 15;

  const int q = q0 + qs * 32 + l31;              // this lane's q row
  bf16x8 aq[4];                                  // Q[q][ds*16 + hi*8 ..+8]
#pragma unroll
  for (int ds = 0; ds < 4; ds++)
    aq[ds] = *(const bf16x8*)(Qb + q * 64 + ds * 16 + hi * 8);

  f32x16 o0 = {}, o1 = {};                       // O^T: d = (r&3)+8*(r>>2)+4*hi (+32 o1)
  float m = -3.0e38f, lsum = 0.f;

  // prologue: stage kt-tile 0 into buf 0 (4 x async16 per thread, 32KB)
#pragma unroll
  for (int c = 0; c < 2; c++) {
    async16(gk + c * (64 * 64), &Ks[0][tid * 8 + c * 4096]);
    async16(gv + c * (32 * 2048), &Vs[0][tid * 8 + c * 4096]);
  }

  for (int it = 0; it < nIter; ++it) {
    const int cur = it & 1;
    __syncthreads();                             // buf[cur] resident (vmcnt drained)
    if (it + 1 < nIter) {                        // prefetch next tile into buf[cur^1]
      const int kt1 = (it + 1) * 128;
#pragma unroll
      for (int c = 0; c < 2; c++) {
        async16(gk + kt1 * 64 + c * (64 * 64), &Ks[cur ^ 1][tid * 8 + c * 4096]);
        async16(gv + kt1 + c * (32 * 2048), &Vs[cur ^ 1][tid * 8 + c * 4096]);
      }
    }
    const bf16* Kc = Ks[cur];
    const bf16* Vc = Vs[cur];

    // QK^T over this wave's kt-half:
    // s[nf] = S[kt = it*128 + halfw*64 + nf*32 + (r&3)+8*(r>>2)+4*hi][q]
    f32x16 s[2] = {};
    __builtin_amdgcn_s_setprio(1);
#pragma unroll
    for (int nf = 0; nf < 2; nf++) {
      const int row = halfw * 64 + nf * 32 + l31;
#pragma unroll
      for (int ds = 0; ds < 4; ds++) {
        bf16x8 kf = *(const bf16x8*)(Kc + row * 64 + (((ds * 2 + hi) ^ swzk) << 3));
        s[nf] = __builtin_amdgcn_mfma_f32_32x32x16_bf16(kf, aq[ds], s[nf], 0, 0, 0);
      }
    }
    __builtin_amdgcn_s_setprio(0);

    if (it == nIter - 1) {                       // diagonal tile mask
#pragma unroll
      for (int nf = 0; nf < 2; nf++)
#pragma unroll
        for (int r = 0; r < 16; r++) {
          const int kt = it * 128 + halfw * 64 + nf * 32 +
                         (r & 3) + 8 * (r >> 2) + 4 * hi;
          if (kt > q) s[nf][r] = -3.0e38f;
        }
    }

    // online softmax over 32 local kt (+partner lane^32 = other 16 rows/32-blk).
    // explicit fmax tree (depth 5) instead of 32-deep serial chain.
    float red[8];
#pragma unroll
    for (int r = 0; r < 8; r++)
      red[r] = fmaxf(fmaxf(s[0][r], s[0][r + 8]), fmaxf(s[1][r], s[1][r + 8]));
#pragma unroll
    for (int st = 4; st >= 1; st >>= 1)
#pragma unroll
      for (int r = 0; r < 4; r++)
        if (r < st) red[r] = fmaxf(red[r], red[r + st]);
    float mx = red[0];
    mx = fmaxf(mx, __shfl_xor(mx, 32));
    if (!__all(mx - m <= 8.0f)) {                // defer-max (T13, THR=8 log2)
      const float mnew = fmaxf(m, mx);
      const float alpha = __builtin_amdgcn_exp2f(m - mnew);
      m = mnew; lsum *= alpha;
#pragma unroll
      for (int r = 0; r < 16; r++) { o0[r] *= alpha; o1[r] *= alpha; }
    }
    float tsp[4] = {0.f, 0.f, 0.f, 0.f};
    unsigned w[2][8];                            // w[nf][k]: kt pair base
                                                 // {0,2,8,10,16,18,24,26}[k]+4*hi
#pragma unroll
    for (int nf = 0; nf < 2; nf++)
#pragma unroll
      for (int k = 0; k < 8; k++) {
        const float pa = __builtin_amdgcn_exp2f(s[nf][2 * k] - m);
        const float pc = __builtin_amdgcn_exp2f(s[nf][2 * k + 1] - m);
        tsp[k & 3] += pa + pc;
        w[nf][k] = pk(pa, pc);
      }
    float ts = (tsp[0] + tsp[1]) + (tsp[2] + tsp[3]);
    ts += __shfl_xor(ts, 32);
    lsum += ts;

    // PV over this wave's kt-half. Chunk c needs pb[j] = P[c*16+hi*8+j][q]:
    //   hi=0: [own w(4h+0..1), partner w(4h+0..1)]
    //   hi=1: [partner w(4h+2..3), own w(4h+2..3)]
    __builtin_amdgcn_s_setprio(1);
#pragma unroll
    for (int nf = 0; nf < 2; nf++) {
#pragma unroll
      for (int hh = 0; hh < 2; hh++) {
        const unsigned w0 = w[nf][hh * 4 + 0], w1 = w[nf][hh * 4 + 1];
        const unsigned w2 = w[nf][hh * 4 + 2], w3 = w[nf][hh * 4 + 3];
        const unsigned rx = (unsigned)__shfl_xor((int)(hi ? w0 : w2), 32);
        const unsigned ry = (unsigned)__shfl_xor((int)(hi ? w1 : w3), 32);
        u32x4 pw;
        pw[0] = hi ? rx : w0;
        pw[1] = hi ? ry : w1;
        pw[2] = hi ? w2 : rx;
        pw[3] = hi ? w3 : ry;
        const bf16x8 pb = __builtin_bit_cast(bf16x8, pw);
        const int c = halfw * 4 + nf * 2 + hh;   // global 16-kt chunk 0..7
        const bf16x8 vf0 = *(const bf16x8*)(Vc + l31 * 128 +
                                            (((c * 2 + hi) ^ swzv) << 3));
        o0 = __builtin_amdgcn_mfma_f32_32x32x16_bf16(vf0, pb, o0, 0, 0, 0);
        const bf16x8 vf1 = *(const bf16x8*)(Vc + (32 + l31) * 128 +
                                            (((c * 2 + hi) ^ swzv) << 3));
        o1 = __builtin_amdgcn_mfma_f32_32x32x16_bf16(vf1, pb, o1, 0, 0, 0);
      }
    }
    __builtin_amdgcn_s_setprio(0);
  }

  // ---- merge the two kt-halves (waves w and w+4 share q rows) ----
  __syncthreads();                               // all LDS use done
  float* oX = (float*)Vs;                        // 8192 f32: [32][256] r-major
  float* mX = (float*)Ks;                        // [2][256]: m then lsum
  const int slot = qs * 64 + lane;               // 0..255
  if (halfw == 1) {
#pragma unroll
    for (int r = 0; r < 16; r++) {
      oX[r * 256 + slot] = o0[r];
      oX[(16 + r) * 256 + slot] = o1[r];
    }
    mX[slot] = m;
    mX[256 + slot] = lsum;
  }
  __syncthreads();
  if (halfw == 0) {
    const float mB = mX[slot], lB = mX[256 + slot];
    const float m12 = fmaxf(m, mB);
    const float aA = __builtin_amdgcn_exp2f(m - m12);
    const float aB = __builtin_amdgcn_exp2f(mB - m12);
    const float inv = 1.0f / (lsum * aA + lB * aB);
    bf16* Op = O + (size_t)(bb * 2048 + q) * 1024 + h * 64;
#pragma unroll
    for (int g = 0; g < 4; g++) {
      bf16x4 v0, v1;
#pragma unroll
      for (int k2 = 0; k2 < 4; k2++) {
        const int r = g * 4 + k2;
        v0[k2] = (bf16)((o0[r] * aA + oX[r * 256 + slot] * aB) * inv);
        v1[k2] = (bf16)((o1[r] * aA + oX[(16 + r) * 256 + slot] * aB) * inv);
      }
      *(bf16x4*)(Op + g * 8 + hi * 4) = v0;
      *(bf16x4*)(Op + 32 + g * 8 + hi * 4) = v1;
    }
  }
}

// ---------------------------------------------------------------- launch
extern "C" void kernel_launch(void* const* d_in, const int* in_sizes, int n_in,
                              void* d_out, int out_size, void* d_ws, size_t ws_size,
                              hipStream_t stream) {
  const float* x     = (const float*)d_in[0];
  const float* Wqkv  = (const float*)d_in[1];
  const float* bqkv  = (const float*)d_in[2];
  const float* Wproj = (const float*)d_in[3];
  const float* bproj = (const float*)d_in[4];
  float* out = (float*)d_out;

  char* p = (char*)d_ws;
  bf16* xbf    = (bf16*)p; p += (size_t)M_ * C_ * 2;     // 8 MB
  bf16* wqkvT  = (bf16*)p; p += (size_t)NQKV * C_ * 2;   // 6 MB
  bf16* wprojT = (bf16*)p; p += (size_t)C_ * C_ * 2;     // 2 MB
  bf16* Qb     = (bf16*)p; p += (size_t)M_ * C_ * 2;     // 8 MB
  bf16* Kb     = (bf16*)p; p += (size_t)M_ * C_ * 2;     // 8 MB
  bf16* Vtb    = (bf16*)p; p += (size_t)M_ * C_ * 2;     // 8 MB
  bf16* AO     = (bf16*)p;                               // 8 MB (total 48 MB)

  prep_k<<<8192, 256, 0, stream>>>(x, xbf, Wqkv, wqkvT, Wproj, wprojT);

  // QKV: m97 geometry — 128x128 tile, grid 32x24 = 768 blocks = 3/CU
  gemm_k<0, 128, 128><<<dim3(M_ / 128, NQKV / 128), 256, 0, stream>>>(
      xbf, wqkvT, bqkv, nullptr, Qb, Kb, Vtb);

  attn_k<<<512, 512, 0, stream>>>(Qb, Kb, Vtb, AO);

  // proj: 64x64 tile — grid 64x16 = 1024 blocks = 4/CU, 32.7 FLOP/B staged
  gemm_k<1, 64, 64><<<dim3(M_ / 64, C_ / 64), 256, 0, stream>>>(
      AO, wprojT, bproj, out, nullptr, nullptr, nullptr);
}